// Round 4
// baseline (514.618 us; speedup 1.0000x reference)
//
#include <hip/hip_runtime.h>

#define NN 2000
#define TT 12

// workspace layout (in floats)
#define XOFF   0          // x buffer: (B,N,C,T) = 16*2000*384
#define SKOFF  12288000   // skip: (B,N,C)
#define CHOFF  13312000   // ch: N*4
#define CMOFF  13320000   // char_m: N*4
#define STOFF  13328000   // stats: 3 layers * 32 (S1[16], S2[16])

typedef _Float16 h2 __attribute__((ext_vector_type(2)));
union U32H2 { unsigned int u; h2 h; };
__device__ __forceinline__ h2 u2h(unsigned int u){ U32H2 v; v.u = u; return v.h; }
__device__ __forceinline__ unsigned int pkh(float a, float b){
  U32H2 v; v.h.x = (_Float16)a; v.h.y = (_Float16)b; return v.u;
}
__device__ __forceinline__ float fsig(float x){ return 1.0f/(1.0f + __expf(-x)); }
__device__ __forceinline__ float ftanh(float x){ return 1.0f - 2.0f/(1.0f + __expf(2.0f*x)); }

__global__ void k_init(float* stats){
  int t = threadIdx.x;
  if (t < 96) stats[t] = 0.0f;
}

__global__ void k_charm(const float* __restrict__ input,
                        const float* __restrict__ charac,
                        float* __restrict__ cm)
{
  int idx = blockIdx.x*256 + threadIdx.x;
  if (idx >= NN*4) return;
  int n = idx >> 2, r = idx & 3;
  int mv = (int)input[TT];
  int m = ((mv % 12) + 12) % 12;
  int m0 = (m + 11) % 12, m2 = (m + 1) % 12;
  const float* base = charac + n*48;
  cm[idx] = (base[m0*4+r] + base[m*4+r] + base[m2*4+r]) * (1.0f/3.0f);
}

__global__ __launch_bounds__(256) void k_ch(const float* __restrict__ adj,
                                            const float* __restrict__ cm,
                                            float* __restrict__ ch)
{
  __shared__ float red[256][4];
  int n = blockIdx.x, t = threadIdx.x;
  float s0=0.f, s1=0.f, s2=0.f, s3=0.f;
  const float* arow = adj + (size_t)n*NN;
  for (int c = t; c < NN; c += 256){
    float a = arow[c];
    float4 v = *reinterpret_cast<const float4*>(cm + c*4);
    s0 = fmaf(a, v.x, s0); s1 = fmaf(a, v.y, s1);
    s2 = fmaf(a, v.z, s2); s3 = fmaf(a, v.w, s3);
  }
  red[t][0]=s0; red[t][1]=s1; red[t][2]=s2; red[t][3]=s3;
  __syncthreads();
  for (int off = 128; off > 0; off >>= 1){
    if (t < off){
      red[t][0]+=red[t+off][0]; red[t][1]+=red[t+off][1];
      red[t][2]+=red[t+off][2]; red[t][3]+=red[t+off][3];
    }
    __syncthreads();
  }
  if (t < 4) ch[n*4+t] = red[0][t];
}

// one tap-pair slot: accf/accg[t] += wpair . xc[(t+JP)%12]
template<int JP>
__device__ __forceinline__ void slot_acc(uint2 w, const unsigned int* x,
                                         float* accf, float* accg)
{
  h2 wf = u2h(w.x), wg = u2h(w.y);
#pragma unroll
  for (int t = 0; t < 12; ++t){
    int ix = t + JP; if (ix >= 12) ix -= 12;      // compile-time
    h2 xv = u2h(x[ix]);
    accf[t] = __builtin_amdgcn_fdot2(wf, xv, accf[t], false);
    accg[t] = __builtin_amdgcn_fdot2(wg, xv, accg[t], false);
  }
}

// conv over a 16-channel half for both channels of role R.
// R=0: A=slice0(lo=0,k=2): pair j'=0 ; B=slice3(lo=11,k=7): j'=0,2,4,6(single)
// R=1: A=slice1(lo=2,k=3): j'=0,2(single); B=slice2(lo=5,k=6): j'=0,2,4
template<int R>
__device__ __forceinline__ void conv_half(
    const unsigned int* __restrict__ xcrow,   // xcb + b*388
    const unsigned int* __restrict__ wbase,   // wfp + p*324
    int c0,
    float* faA, float* gaA, float* faB, float* gaB)
{
  for (int c = c0; c < c0+16; ++c){
    const uint4* xp = reinterpret_cast<const uint4*>(xcrow + c*12);
    uint4 xa = xp[0], xb = xp[1], xd = xp[2];
    unsigned int x[12] = {xa.x,xa.y,xa.z,xa.w, xb.x,xb.y,xb.z,xb.w, xd.x,xd.y,xd.z,xd.w};
    const unsigned int* wp = wbase + c*10;
    uint2 w0 = *reinterpret_cast<const uint2*>(wp+0);
    uint2 w1 = *reinterpret_cast<const uint2*>(wp+2);
    uint2 w2 = *reinterpret_cast<const uint2*>(wp+4);
    uint2 w3 = *reinterpret_cast<const uint2*>(wp+6);
    uint2 w4 = *reinterpret_cast<const uint2*>(wp+8);
    if (R == 0){
      slot_acc<0>(w0, x, faA, gaA);
      slot_acc<0>(w1, x, faB, gaB);
      slot_acc<2>(w2, x, faB, gaB);
      slot_acc<4>(w3, x, faB, gaB);
      slot_acc<6>(w4, x, faB, gaB);
    } else {
      slot_acc<0>(w0, x, faA, gaA);
      slot_acc<2>(w1, x, faA, gaA);
      slot_acc<0>(w2, x, faB, gaB);
      slot_acc<2>(w3, x, faB, gaB);
      slot_acc<4>(w4, x, faB, gaB);
    }
  }
}

__global__ __launch_bounds__(256,3) void k_layer(
    int layer,
    float* __restrict__ xbuf, float* __restrict__ skipbuf,
    const float* __restrict__ ch, float* stats,
    const float* __restrict__ input,
    const float* __restrict__ Wcw, const float* __restrict__ bcw,
    const float* __restrict__ Wcb, const float* __restrict__ bcb,
    const float* __restrict__ Wgw, const float* __restrict__ bgw,
    const float* __restrict__ Wgb, const float* __restrict__ bgb,
    const float* __restrict__ Wrw, const float* __restrict__ brw,
    const float* __restrict__ Wrb, const float* __restrict__ brb,
    const float* __restrict__ start_w, const float* __restrict__ start_b,
    const float* __restrict__ sk0w, const float* __restrict__ sk0b,
    const float* __restrict__ skw_all, const float* __restrict__ skb_all,
    const float* __restrict__ lnw_all, const float* __restrict__ lnb_all)
{
  __shared__ unsigned int wfp[16*324];   // per role-row p: 32 c x [5 slots x (f,g)]
  __shared__ unsigned int xcb[8*388];    // circular f16 pairs: [b][c*12+s]
  __shared__ unsigned int gsb[8*196];    // gated out f16 t-pairs: [b][oc*6+tp]
  __shared__ float rwv[1056];            // 32x33
  __shared__ float ubuf[1088];           // L0: sw|sb|s0w|s0b|xin ; L>0: lnw|lnb
  __shared__ float skwv[384], skbv[32];
  __shared__ float fbias[32], gbias[32], rbv[32];
  __shared__ float chs[4], chb[16];
  __shared__ float muv[16], rsv[16];
  __shared__ float red1[32], red2[32];

  const int tid = threadIdx.x;
  const int n = blockIdx.x;

  float* swv  = ubuf;        // 64   (layer 0)
  float* sbv  = ubuf + 64;   // 32
  float* s0wv = ubuf + 96;   // 768
  float* s0bv = ubuf + 864;  // 32
  float* xin  = ubuf + 896;  // 8*24
  float* lnw  = ubuf;        // 384  (layer > 0)
  float* lnb  = ubuf + 384;  // 384

  for (int i = tid; i < 4;  i += 256) chs[i] = ch[n*4+i];
  for (int i = tid; i < 16; i += 256) chb[i] = ch[((i>>2)*500 + (n>>2))*4 + (i&3)];
  for (int i = tid; i < 32; i += 256) skbv[i] = skb_all[layer*32+i];
  for (int i = tid; i < 384; i += 256) skwv[i] = skw_all[layer*384+i];
  if (layer == 0){
    for (int i = tid; i < 64; i += 256) swv[i] = start_w[i];
    for (int i = tid; i < 32; i += 256){ sbv[i] = start_b[i]; s0bv[i] = sk0b[i]; }
    for (int i = tid; i < 768; i += 256) s0wv[i] = sk0w[i];
  } else {
    for (int i = tid; i < 384; i += 256){
      int c = i/12, t = i%12;
      size_t o = (((size_t)(layer-1)*32 + c)*NN + n)*12 + t;
      lnw[i] = lnw_all[o]; lnb[i] = lnb_all[o];
    }
    if (tid < 16){
      float S1 = stats[(layer-1)*32 + tid];
      float S2 = stats[(layer-1)*32 + 16 + tid];
      const float M = 768000.0f;
      float mu = S1 / M;
      muv[tid] = mu;
      rsv[tid] = rsqrtf(S2/M - mu*mu + 1e-5f);
    }
  }
  __syncthreads();

  const float c0v = chs[0], c1v = chs[1], c2v = chs[2], c3v = chs[3];
  // ---- weight gen: tap-pair packed f16, (f,g) adjacent ----
  for (int idx = tid; idx < 2560; idx += 256){
    int r    = (idx >= 1280) ? 1 : 0;
    int rem  = idx - r*1280;
    int o    = rem / 160;
    int rem2 = rem - o*160;
    int c    = rem2 / 5;
    int slot = rem2 - c*5;
    int j0 = (r==0) ? ((slot==0)?0:(slot==1)?11:(slot==2)?13:(slot==3)?15:17)
                    : ((slot==0)?2:(slot==1)?4:(slot==2)?5:(slot==3)?7:9);
    bool has1 = (r==0) ? (slot!=4) : (slot!=1);
    int col = layer*4608 + o*576 + c*18 + j0;
    float wf0 = fmaf(c0v, Wcw[col], fmaf(c1v, Wcw[13824+col],
                fmaf(c2v, Wcw[27648+col], fmaf(c3v, Wcw[41472+col], bcw[col]))));
    float wg0 = fmaf(c0v, Wgw[col], fmaf(c1v, Wgw[13824+col],
                fmaf(c2v, Wgw[27648+col], fmaf(c3v, Wgw[41472+col], bgw[col]))));
    float wf1 = 0.0f, wg1 = 0.0f;
    if (has1){
      int col1 = col + 1;
      wf1 = fmaf(c0v, Wcw[col1], fmaf(c1v, Wcw[13824+col1],
            fmaf(c2v, Wcw[27648+col1], fmaf(c3v, Wcw[41472+col1], bcw[col1]))));
      wg1 = fmaf(c0v, Wgw[col1], fmaf(c1v, Wgw[13824+col1],
            fmaf(c2v, Wgw[27648+col1], fmaf(c3v, Wgw[41472+col1], bgw[col1]))));
    }
    int row = r*8 + o;
    wfp[row*324 + c*10 + slot*2]     = pkh(wf0, wf1);
    wfp[row*324 + c*10 + slot*2 + 1] = pkh(wg0, wg1);
  }
  for (int i = tid; i < 1024; i += 256){
    int col = layer*1024 + i;
    float v = fmaf(c0v, Wrw[col], fmaf(c1v, Wrw[3072+col],
              fmaf(c2v, Wrw[6144+col], fmaf(c3v, Wrw[9216+col], brw[col]))));
    rwv[(i>>5)*33 + (i&31)] = v;
  }
  if (tid < 32){
    int oc = tid;
    int s = oc >> 3;
    int v = ((n&3)<<3) + (oc&7);               // bias reshuffle: column
    int col = layer*32 + v;
    const float* cb4 = &chb[s*4];              // bias reshuffle: node s*500+n/4
    fbias[oc] = fmaf(cb4[0], Wcb[col], fmaf(cb4[1], Wcb[96+col],
                fmaf(cb4[2], Wcb[192+col], fmaf(cb4[3], Wcb[288+col], bcb[col]))));
    gbias[oc] = fmaf(cb4[0], Wgb[col], fmaf(cb4[1], Wgb[96+col],
                fmaf(cb4[2], Wgb[192+col], fmaf(cb4[3], Wgb[288+col], bgb[col]))));
    int colr = layer*32 + oc;
    rbv[oc] = fmaf(c0v, Wrb[colr], fmaf(c1v, Wrb[96+colr],
              fmaf(c2v, Wrb[192+colr], fmaf(c3v, Wrb[288+colr], brb[colr]))));
  }

  const int p     = tid >> 4;
  const int chalf = (tid >> 3) & 1;
  const int b     = tid & 7;
  const int oc_sel = chalf ? (24 - (p & 8) + (p & 7)) : p;

  for (int bo = 0; bo < 2; ++bo){
    // ---- phase A: stage circular f16 pairs for 8 batches ----
    if (layer == 0){
      if (bo == 0) __syncthreads();            // wfp/ubuf ready before first use
      if (tid < 192){
        int bb = tid/24, r = tid%24, d = r/12, t = r%12;
        xin[bb*24+r] = input[(((size_t)(bo*8+bb)*2 + d)*NN + n)*13 + t];
      }
      __syncthreads();
      {
        int bb = tid >> 5, c = tid & 31;
        float xv[12];
#pragma unroll
        for (int t = 0; t < 12; ++t)
          xv[t] = fmaf(swv[c*2], xin[bb*24+t], fmaf(swv[c*2+1], xin[bb*24+12+t], sbv[c]));
        unsigned int pk[12];
#pragma unroll
        for (int s = 0; s < 12; ++s) pk[s] = pkh(xv[s], xv[(s+1)%12]);
        uint4* dst = reinterpret_cast<uint4*>(&xcb[bb*388 + c*12]);
        dst[0] = make_uint4(pk[0],pk[1],pk[2],pk[3]);
        dst[1] = make_uint4(pk[4],pk[5],pk[6],pk[7]);
        dst[2] = make_uint4(pk[8],pk[9],pk[10],pk[11]);
      }
    } else {
      if (bo == 0) __syncthreads();            // muv/ln/wfp ready
      {
        int bb = tid >> 5, c = tid & 31;
        int bg = bo*8 + bb;
        const float4* src = reinterpret_cast<const float4*>(
            xbuf + ((size_t)bg*NN + n)*384 + c*12);
        float4 v0 = src[0], v1 = src[1], v2 = src[2];
        float xv[12] = {v0.x,v0.y,v0.z,v0.w, v1.x,v1.y,v1.z,v1.w, v2.x,v2.y,v2.z,v2.w};
        float mu = muv[bg], rs = rsv[bg];
#pragma unroll
        for (int t = 0; t < 12; ++t)
          xv[t] = fmaf((xv[t]-mu)*rs, lnw[c*12+t], lnb[c*12+t]);
        unsigned int pk[12];
#pragma unroll
        for (int s = 0; s < 12; ++s) pk[s] = pkh(xv[s], xv[(s+1)%12]);
        uint4* dst = reinterpret_cast<uint4*>(&xcb[bb*388 + c*12]);
        dst[0] = make_uint4(pk[0],pk[1],pk[2],pk[3]);
        dst[1] = make_uint4(pk[4],pk[5],pk[6],pk[7]);
        dst[2] = make_uint4(pk[8],pk[9],pk[10],pk[11]);
      }
    }
    __syncthreads();

    // ---- phase B: dot2 conv over this thread's c-half ----
    {
      float faA[12], gaA[12], faB[12], gaB[12];
      const int ocA = p, ocB = 24 - (p & 8) + (p & 7);
      const float fbA = fbias[ocA]*0.5f, gbA = gbias[ocA]*0.5f;   // halves sum to full bias
      const float fbB = fbias[ocB]*0.5f, gbB = gbias[ocB]*0.5f;
#pragma unroll
      for (int t = 0; t < 12; ++t){ faA[t]=fbA; gaA[t]=gbA; faB[t]=fbB; gaB[t]=gbB; }
      const unsigned int* xcrow = xcb + b*388;
      const unsigned int* wbase = wfp + p*324;
      if (p < 8) conv_half<0>(xcrow, wbase, chalf*16, faA, gaA, faB, gaB);
      else       conv_half<1>(xcrow, wbase, chalf*16, faA, gaA, faB, gaB);
      // combine the two c-halves
#pragma unroll
      for (int t = 0; t < 12; ++t){
        faA[t] += __shfl_xor(faA[t], 8);
        gaA[t] += __shfl_xor(gaA[t], 8);
        faB[t] += __shfl_xor(faB[t], 8);
        gaB[t] += __shfl_xor(gaB[t], 8);
      }
      // finalize one channel per thread
      const int oc = oc_sel;
      float gg[12];
#pragma unroll
      for (int t = 0; t < 12; ++t){
        float fs = chalf ? faB[t] : faA[t];
        float gs = chalf ? gaB[t] : gaA[t];
        gg[t] = ftanh(fs) * fsig(gs);
      }
      float sk = skbv[oc];
#pragma unroll
      for (int t = 0; t < 12; ++t) sk = fmaf(gg[t], skwv[oc*12+t], sk);
      size_t so = ((size_t)(bo*8+b)*NN + n)*32 + oc;
      if (layer == 0){
        float s0 = s0bv[oc];
#pragma unroll
        for (int r = 0; r < 24; ++r) s0 = fmaf(xin[b*24+r], s0wv[oc*24+r], s0);
        skipbuf[so] = sk + s0;
      } else {
        skipbuf[so] += sk;
      }
      uint2* gp = reinterpret_cast<uint2*>(&gsb[b*196 + oc*6]);
      gp[0] = make_uint2(pkh(gg[0],gg[1]),  pkh(gg[2],gg[3]));
      gp[1] = make_uint2(pkh(gg[4],gg[5]),  pkh(gg[6],gg[7]));
      gp[2] = make_uint2(pkh(gg[8],gg[9]),  pkh(gg[10],gg[11]));
    }
    __syncthreads();

    // ---- phase C: residual matmul + residual add + stats ----
    {
      const int oc = oc_sel;
      const uint4* xr4 = reinterpret_cast<const uint4*>(&xcb[b*388 + oc*12]);
      uint4 ua = xr4[0], ub = xr4[1], ud = xr4[2];
      unsigned int xu[12] = {ua.x,ua.y,ua.z,ua.w, ub.x,ub.y,ub.z,ub.w, ud.x,ud.y,ud.z,ud.w};
      float acc[12];
      const float rb = rbv[oc];
#pragma unroll
      for (int t = 0; t < 12; ++t) acc[t] = rb + (float)(u2h(xu[t]).x);
      for (int c = 0; c < 32; ++c){
        float rv = rwv[oc*33 + c];
        const uint2* gp = reinterpret_cast<const uint2*>(&gsb[b*196 + c*6]);
        uint2 g0 = gp[0], g1 = gp[1], g2 = gp[2];
        h2 h0 = u2h(g0.x), h1 = u2h(g0.y), h2v = u2h(g1.x),
           h3 = u2h(g1.y), h4 = u2h(g2.x), h5 = u2h(g2.y);
        acc[0] = fmaf((float)h0.x, rv, acc[0]);  acc[1] = fmaf((float)h0.y, rv, acc[1]);
        acc[2] = fmaf((float)h1.x, rv, acc[2]);  acc[3] = fmaf((float)h1.y, rv, acc[3]);
        acc[4] = fmaf((float)h2v.x, rv, acc[4]); acc[5] = fmaf((float)h2v.y, rv, acc[5]);
        acc[6] = fmaf((float)h3.x, rv, acc[6]);  acc[7] = fmaf((float)h3.y, rv, acc[7]);
        acc[8] = fmaf((float)h4.x, rv, acc[8]);  acc[9] = fmaf((float)h4.y, rv, acc[9]);
        acc[10]= fmaf((float)h5.x, rv, acc[10]); acc[11]= fmaf((float)h5.y, rv, acc[11]);
      }
      float* xo = xbuf + ((size_t)(bo*8+b)*NN + n)*384 + oc*12;
      float4* xo4 = reinterpret_cast<float4*>(xo);
      xo4[0] = make_float4(acc[0],acc[1],acc[2],acc[3]);
      xo4[1] = make_float4(acc[4],acc[5],acc[6],acc[7]);
      xo4[2] = make_float4(acc[8],acc[9],acc[10],acc[11]);
      float s1 = 0.0f, s2 = 0.0f;
#pragma unroll
      for (int t = 0; t < 12; ++t){ s1 += acc[t]; s2 = fmaf(acc[t], acc[t], s2); }
      s1 += __shfl_xor(s1, 8);  s2 += __shfl_xor(s2, 8);
      s1 += __shfl_xor(s1, 16); s2 += __shfl_xor(s2, 16);
      s1 += __shfl_xor(s1, 32); s2 += __shfl_xor(s2, 32);
      int lane = tid & 63, wv = tid >> 6;
      if (lane < 8){ red1[wv*8 + lane] = s1; red2[wv*8 + lane] = s2; }
    }
    __syncthreads();
    if (tid < 16){
      int bb = tid & 7; bool w2 = tid >= 8;
      float s = 0.0f;
      for (int w = 0; w < 4; ++w) s += w2 ? red2[w*8+bb] : red1[w*8+bb];
      atomicAdd(&stats[layer*32 + (w2 ? 16 : 0) + bo*8 + bb], s);
    }
    __syncthreads();
  }
}

__global__ __launch_bounds__(256) void k_final(
    const float* __restrict__ xbuf, const float* __restrict__ skipbuf,
    const float* __restrict__ stats,
    const float* __restrict__ lnw_all, const float* __restrict__ lnb_all,
    const float* __restrict__ skEw, const float* __restrict__ skEb,
    const float* __restrict__ e1w, const float* __restrict__ e1b,
    const float* __restrict__ e2w, const float* __restrict__ e2b,
    float* __restrict__ out)
{
  __shared__ float lnw[384], lnb[384], skE[384];
  __shared__ float e1[32*33];
  __shared__ float e1bv[32], e2v[32], skEbv[32];
  __shared__ float muv[16], rsv[16];
  __shared__ float skf[8][33];
  const int tid = threadIdx.x, n = blockIdx.x;
  for (int i = tid; i < 384; i += 256){
    int c = i/12, t = i%12;
    size_t o = (((size_t)2*32 + c)*NN + n)*12 + t;
    lnw[i] = lnw_all[o]; lnb[i] = lnb_all[o];
    skE[i] = skEw[i];
  }
  for (int i = tid; i < 1024; i += 256) e1[(i>>5)*33 + (i&31)] = e1w[i];
  if (tid < 32){ e1bv[tid] = e1b[tid]; e2v[tid] = e2w[tid]; skEbv[tid] = skEb[tid]; }
  if (tid < 16){
    float S1 = stats[64+tid], S2 = stats[80+tid];
    const float M = 768000.0f;
    float mu = S1/M; muv[tid] = mu;
    rsv[tid] = rsqrtf(S2/M - mu*mu + 1e-5f);
  }
  __syncthreads();
  const float e2b0 = e2b[0];
  for (int bo = 0; bo < 2; ++bo){
    const int g = tid >> 5, c = tid & 31, b = bo*8 + g;
    const float4* xp = reinterpret_cast<const float4*>(xbuf + ((size_t)b*NN+n)*384 + c*12);
    float4 xA = xp[0], xB = xp[1], xC = xp[2];
    float xr[12] = {xA.x,xA.y,xA.z,xA.w, xB.x,xB.y,xB.z,xB.w, xC.x,xC.y,xC.z,xC.w};
    const float mu = muv[b], rs = rsv[b];
    float se = 0.0f;
#pragma unroll
    for (int t = 0; t < 12; ++t){
      float xv = fmaf((xr[t]-mu)*rs, lnw[c*12+t], lnb[c*12+t]);
      se = fmaf(xv, skE[c*12+t], se);
    }
    float sk = se + skEbv[c] + skipbuf[((size_t)b*NN+n)*32 + c];
    skf[g][c] = fmaxf(sk, 0.0f);
    __syncthreads();
    float acc = e1bv[c];
#pragma unroll
    for (int cc = 0; cc < 32; ++cc) acc = fmaf(skf[g][cc], e1[c*33+cc], acc);
    float y1 = fmaxf(acc, 0.0f);
    float part = y1 * e2v[c];
#pragma unroll
    for (int off = 16; off > 0; off >>= 1) part += __shfl_down(part, off, 32);
    if (c == 0) out[(size_t)b*NN + n] = part + e2b0;
    __syncthreads();
  }
}

extern "C" void kernel_launch(void* const* d_in, const int* in_sizes, int n_in,
                              void* d_out, int out_size, void* d_ws, size_t ws_size,
                              hipStream_t stream)
{
  (void)in_sizes; (void)n_in; (void)out_size; (void)ws_size;
  const float* input   = (const float*)d_in[0];
  const float* adj     = (const float*)d_in[1];
  const float* charac  = (const float*)d_in[2];
  const float* Wcw     = (const float*)d_in[3];
  const float* bcw     = (const float*)d_in[4];
  const float* Wcb     = (const float*)d_in[5];
  const float* bcb     = (const float*)d_in[6];
  const float* Wgw     = (const float*)d_in[7];
  const float* bgw     = (const float*)d_in[8];
  const float* Wgb     = (const float*)d_in[9];
  const float* bgb     = (const float*)d_in[10];
  const float* Wrw     = (const float*)d_in[11];
  const float* brw     = (const float*)d_in[12];
  const float* Wrb     = (const float*)d_in[13];
  const float* brb     = (const float*)d_in[14];
  const float* start_w = (const float*)d_in[15];
  const float* start_b = (const float*)d_in[16];
  const float* sk0w    = (const float*)d_in[17];
  const float* sk0b    = (const float*)d_in[18];
  const float* skw     = (const float*)d_in[19];
  const float* skb     = (const float*)d_in[20];
  const float* skEw    = (const float*)d_in[21];
  const float* skEb    = (const float*)d_in[22];
  const float* lnw     = (const float*)d_in[23];
  const float* lnb     = (const float*)d_in[24];
  const float* e1w     = (const float*)d_in[25];
  const float* e1b     = (const float*)d_in[26];
  const float* e2w     = (const float*)d_in[27];
  const float* e2b     = (const float*)d_in[28];

  float* ws     = (float*)d_ws;
  float* xbuf   = ws + XOFF;
  float* skipb  = ws + SKOFF;
  float* chbuf  = ws + CHOFF;
  float* cmbuf  = ws + CMOFF;
  float* stats  = ws + STOFF;
  float* outp   = (float*)d_out;

  k_init<<<1, 128, 0, stream>>>(stats);
  k_charm<<<32, 256, 0, stream>>>(input, charac, cmbuf);
  k_ch<<<NN, 256, 0, stream>>>(adj, cmbuf, chbuf);
  for (int layer = 0; layer < 3; ++layer){
    k_layer<<<NN, 256, 0, stream>>>(layer, xbuf, skipb, chbuf, stats, input,
        Wcw, bcw, Wcb, bcb, Wgw, bgw, Wgb, bgb, Wrw, brw, Wrb, brb,
        start_w, start_b, sk0w, sk0b, skw, skb, lnw, lnb);
  }
  k_final<<<NN, 256, 0, stream>>>(xbuf, skipb, stats, lnw, lnb,
      skEw, skEb, e1w, e1b, e2w, e2b, outp);
}

// Round 5
// 312.759 us; speedup vs baseline: 1.6454x; 1.6454x over previous
//
#include <hip/hip_runtime.h>

#define NN 2000
#define TT 12

// workspace layout (in floats)
#define XOFF   0          // x buffer: (B,N,T,C) = 16*2000*12*32
#define SKOFF  12288000   // skip: (B,N,C)
#define CHOFF  13312000   // ch: N*4
#define CMOFF  13320000   // char_m: N*4
#define STOFF  13328000   // stats: 3 layers * 32 (S1[16], S2[16])

typedef __fp16 f16x8 __attribute__((ext_vector_type(8)));
typedef float  f32x4 __attribute__((ext_vector_type(4)));

union U32H2 { unsigned int u; __fp16 h[2]; };
__device__ __forceinline__ unsigned int pkh(float a, float b){
  U32H2 v; v.h[0] = (__fp16)a; v.h[1] = (__fp16)b; return v.u;
}
__device__ __forceinline__ float fsig(float x){ return 1.0f/(1.0f + __expf(-x)); }
__device__ __forceinline__ float ftanh(float x){ return 1.0f - 2.0f/(1.0f + __expf(2.0f*x)); }

__global__ void k_init(float* stats){
  int t = threadIdx.x;
  if (t < 96) stats[t] = 0.0f;
}

__global__ void k_charm(const float* __restrict__ input,
                        const float* __restrict__ charac,
                        float* __restrict__ cm)
{
  int idx = blockIdx.x*256 + threadIdx.x;
  if (idx >= NN*4) return;
  int n = idx >> 2, r = idx & 3;
  int mv = (int)input[TT];
  int m = ((mv % 12) + 12) % 12;
  int m0 = (m + 11) % 12, m2 = (m + 1) % 12;
  const float* base = charac + n*48;
  cm[idx] = (base[m0*4+r] + base[m*4+r] + base[m2*4+r]) * (1.0f/3.0f);
}

__global__ __launch_bounds__(256) void k_ch(const float* __restrict__ adj,
                                            const float* __restrict__ cm,
                                            float* __restrict__ ch)
{
  __shared__ float red[256][4];
  int n = blockIdx.x, t = threadIdx.x;
  float s0=0.f, s1=0.f, s2=0.f, s3=0.f;
  const float* arow = adj + (size_t)n*NN;
  for (int c = t; c < NN; c += 256){
    float a = arow[c];
    float4 v = *reinterpret_cast<const float4*>(cm + c*4);
    s0 = fmaf(a, v.x, s0); s1 = fmaf(a, v.y, s1);
    s2 = fmaf(a, v.z, s2); s3 = fmaf(a, v.w, s3);
  }
  red[t][0]=s0; red[t][1]=s1; red[t][2]=s2; red[t][3]=s3;
  __syncthreads();
  for (int off = 128; off > 0; off >>= 1){
    if (t < off){
      red[t][0]+=red[t+off][0]; red[t][1]+=red[t+off][1];
      red[t][2]+=red[t+off][2]; red[t][3]+=red[t+off][3];
    }
    __syncthreads();
  }
  if (t < 4) ch[n*4+t] = red[0][t];
}

// ---------------------------------------------------------------------------
// k_layer: per-node MFMA. A[64][224] f16 (rows 0-31 filter, 32-63 gate;
// k = jj*32 + c), B chunk for K-step jj = xh[(nt+jj)%12][b][c] (f16, x stored
// [t][b][c]). C tile (mt,nt): row=oc-in-tile, col=b. Residual GEMM: K=32,
// A=rwh[32][32], B=gh (gated, [t][b][c]). Strides: Ah 232, xh/gh/rwh 40
// (16B-aligned rows, <=2-way LDS bank aliasing = free).
// ---------------------------------------------------------------------------
__global__ __launch_bounds__(256,2) void k_layer(
    int layer,
    float* __restrict__ xbuf, float* __restrict__ skipbuf,
    const float* __restrict__ ch, float* stats,
    const float* __restrict__ input,
    const float* __restrict__ Wcw, const float* __restrict__ bcw,
    const float* __restrict__ Wcb, const float* __restrict__ bcb,
    const float* __restrict__ Wgw, const float* __restrict__ bgw,
    const float* __restrict__ Wgb, const float* __restrict__ bgb,
    const float* __restrict__ Wrw, const float* __restrict__ brw,
    const float* __restrict__ Wrb, const float* __restrict__ brb,
    const float* __restrict__ start_w, const float* __restrict__ start_b,
    const float* __restrict__ sk0w, const float* __restrict__ sk0b,
    const float* __restrict__ skw_all, const float* __restrict__ skb_all,
    const float* __restrict__ lnw_all, const float* __restrict__ lnb_all)
{
  __shared__ __fp16 Ah[64*232];      // 29696 B
  __shared__ __fp16 xh[12*16*40];    // 15360 B
  __shared__ __fp16 gh[12*16*40];    // 15360 B
  __shared__ __fp16 rwh[32*40];      //  2560 B
  __shared__ float skred[32*16*2];   //  4096 B
  __shared__ float wred[4*16*2];     //   512 B
  __shared__ float ubuf[1280];       //  5120 B  (L0: sw|sb|s0w|s0b|xin ; L>0: lnw|lnb)
  __shared__ float skwv[384];
  __shared__ float skbv[32], fbias[32], gbias[32], rbv[32];
  __shared__ float chs[4], chb[16], muv[16], rsv[16];

  const int tid = threadIdx.x;
  const int n = blockIdx.x;

  float* swv  = ubuf;        // 64   (layer 0)
  float* sbv  = ubuf + 64;   // 32
  float* s0wv = ubuf + 96;   // 768
  float* s0bv = ubuf + 864;  // 32
  float* xin  = ubuf + 896;  // 384 = 16 b x 24
  float* lnwv = ubuf;        // 384  (layer > 0), [c*12+t]
  float* lnbv = ubuf + 384;  // 384

  // ---- phase 0: constants, zero A ----
  for (int i = tid; i < 4;  i += 256) chs[i] = ch[n*4+i];
  for (int i = tid; i < 16; i += 256) chb[i] = ch[((i>>2)*500 + (n>>2))*4 + (i&3)];
  for (int i = tid; i < 32; i += 256) skbv[i] = skb_all[layer*32+i];
  for (int i = tid; i < 384; i += 256) skwv[i] = skw_all[layer*384+i];
  if (layer == 0){
    for (int i = tid; i < 64; i += 256) swv[i] = start_w[i];
    for (int i = tid; i < 32; i += 256){ sbv[i] = start_b[i]; s0bv[i] = sk0b[i]; }
    for (int i = tid; i < 768; i += 256) s0wv[i] = sk0w[i];
    for (int i = tid; i < 384; i += 256){
      int bb = i/24, r = i%24, d = r/12, t = r%12;
      xin[i] = input[(((size_t)bb*2 + d)*NN + n)*13 + t];
    }
  } else {
    for (int i = tid; i < 384; i += 256){
      int c = i/12, t = i%12;
      size_t o = (((size_t)(layer-1)*32 + c)*NN + n)*12 + t;
      lnwv[i] = lnw_all[o]; lnbv[i] = lnb_all[o];
    }
    if (tid < 16){
      float S1 = stats[(layer-1)*32 + tid];
      float S2 = stats[(layer-1)*32 + 16 + tid];
      const float M = 768000.0f;
      float mu = S1 / M;
      muv[tid] = mu;
      rsv[tid] = rsqrtf(S2/M - mu*mu + 1e-5f);
    }
  }
  {
    unsigned int* az = reinterpret_cast<unsigned int*>(Ah);
    for (int i = tid; i < 7424; i += 256) az[i] = 0u;
  }
  __syncthreads();

  // ---- phase 1: weight gen (coalesced over col) + rw + bias + x staging ----
  const float c0v = chs[0], c1v = chs[1], c2v = chs[2], c3v = chs[3];
  for (int i = tid; i < 4608; i += 256){
    int o   = i / 576;
    int rem = i - o*576;
    int c   = rem / 18;
    int u   = rem - c*18;
    int s   = (u >= 2) + (u >= 5) + (u >= 11);
    int lo  = (s == 0) ? 0 : ((s == 1) ? 2 : ((s == 2) ? 5 : 11));
    int jj  = u - lo;
    int m   = s*8 + o;
    int k   = jj*32 + c;
    int col = layer*4608 + i;
    float wf = fmaf(c0v, Wcw[col], fmaf(c1v, Wcw[13824+col],
               fmaf(c2v, Wcw[27648+col], fmaf(c3v, Wcw[41472+col], bcw[col]))));
    float wg = fmaf(c0v, Wgw[col], fmaf(c1v, Wgw[13824+col],
               fmaf(c2v, Wgw[27648+col], fmaf(c3v, Wgw[41472+col], bgw[col]))));
    Ah[m*232 + k]        = (__fp16)wf;
    Ah[(32 + m)*232 + k] = (__fp16)wg;
  }
  for (int i = tid; i < 1024; i += 256){
    int col = layer*1024 + i;
    float v = fmaf(c0v, Wrw[col], fmaf(c1v, Wrw[3072+col],
              fmaf(c2v, Wrw[6144+col], fmaf(c3v, Wrw[9216+col], brw[col]))));
    rwh[(i>>5)*40 + (i&31)] = (__fp16)v;
  }
  if (tid < 32){
    int oc = tid;
    int s = oc >> 3;
    int v = ((n&3)<<3) + (oc&7);               // bias reshuffle: column
    int col = layer*32 + v;
    const float* cb4 = &chb[s*4];              // bias reshuffle: node s*500+n/4
    fbias[oc] = fmaf(cb4[0], Wcb[col], fmaf(cb4[1], Wcb[96+col],
                fmaf(cb4[2], Wcb[192+col], fmaf(cb4[3], Wcb[288+col], bcb[col]))));
    gbias[oc] = fmaf(cb4[0], Wgb[col], fmaf(cb4[1], Wgb[96+col],
                fmaf(cb4[2], Wgb[192+col], fmaf(cb4[3], Wgb[288+col], bgb[col]))));
    int colr = layer*32 + oc;
    rbv[oc] = fmaf(c0v, Wrb[colr], fmaf(c1v, Wrb[96+colr],
              fmaf(c2v, Wrb[192+colr], fmaf(c3v, Wrb[288+colr], brb[colr]))));
  }
  if (tid < 192){
    int b = tid / 12, t = tid - (tid/12)*12;
    float xv[32];
    if (layer == 0){
      float xa = xin[b*24 + t], xb2 = xin[b*24 + 12 + t];
#pragma unroll
      for (int c = 0; c < 32; ++c)
        xv[c] = fmaf(swv[c*2], xa, fmaf(swv[c*2+1], xb2, sbv[c]));
    } else {
      const float4* src = reinterpret_cast<const float4*>(
          xbuf + (((size_t)b*NN + n)*12 + t)*32);
      float mu = muv[b], rs = rsv[b];
#pragma unroll
      for (int c4 = 0; c4 < 8; ++c4){
        float4 v = src[c4];
        int c = c4*4;
        xv[c]   = fmaf((v.x-mu)*rs, lnwv[(c)*12+t],   lnbv[(c)*12+t]);
        xv[c+1] = fmaf((v.y-mu)*rs, lnwv[(c+1)*12+t], lnbv[(c+1)*12+t]);
        xv[c+2] = fmaf((v.z-mu)*rs, lnwv[(c+2)*12+t], lnbv[(c+2)*12+t]);
        xv[c+3] = fmaf((v.w-mu)*rs, lnwv[(c+3)*12+t], lnbv[(c+3)*12+t]);
      }
    }
    unsigned int pk[16];
#pragma unroll
    for (int j = 0; j < 16; ++j) pk[j] = pkh(xv[2*j], xv[2*j+1]);
    uint4* dst = reinterpret_cast<uint4*>(&xh[(t*16 + b)*40]);
    dst[0] = make_uint4(pk[0], pk[1], pk[2], pk[3]);
    dst[1] = make_uint4(pk[4], pk[5], pk[6], pk[7]);
    dst[2] = make_uint4(pk[8], pk[9], pk[10], pk[11]);
    dst[3] = make_uint4(pk[12],pk[13],pk[14],pk[15]);
  }
  __syncthreads();

  // ---- phase 2: conv via MFMA + activation + gated store + skip partials ----
  const int lane = tid & 63, w = tid >> 6;
  const int h = w & 1, nh = w >> 1;
  const int r16 = lane & 15, hi4 = lane >> 4;
  const int c0 = hi4*8;
  const int oc0 = h*16 + hi4*4;

  f16x8 aF[7], aG[7];
#pragma unroll
  for (int jj = 0; jj < 7; ++jj){
    aF[jj] = *reinterpret_cast<const f16x8*>(&Ah[(h*16 + r16)*232 + jj*32 + c0]);
    aG[jj] = *reinterpret_cast<const f16x8*>(&Ah[(32 + h*16 + r16)*232 + jj*32 + c0]);
  }
  float fb4[4], gb4[4], rb4[4];
#pragma unroll
  for (int i2 = 0; i2 < 4; ++i2){
    fb4[i2] = fbias[oc0+i2]; gb4[i2] = gbias[oc0+i2]; rb4[i2] = rbv[oc0+i2];
  }
  float sv[4] = {0.f, 0.f, 0.f, 0.f};
#pragma unroll
  for (int q = 0; q < 6; ++q){
    int nt = nh*6 + q;
    f32x4 accf = {0.f,0.f,0.f,0.f}, accg = {0.f,0.f,0.f,0.f};
#pragma unroll
    for (int jj = 0; jj < 7; ++jj){
      int tp = nt + jj; if (tp >= 12) tp -= 12;
      f16x8 bf = *reinterpret_cast<const f16x8*>(&xh[(tp*16 + r16)*40 + c0]);
      accf = __builtin_amdgcn_mfma_f32_16x16x32_f16(aF[jj], bf, accf, 0, 0, 0);
      accg = __builtin_amdgcn_mfma_f32_16x16x32_f16(aG[jj], bf, accg, 0, 0, 0);
    }
    float gv4[4];
#pragma unroll
    for (int i2 = 0; i2 < 4; ++i2){
      float fv = ftanh(accf[i2] + fb4[i2]);
      float gg = fsig(accg[i2] + gb4[i2]);
      gv4[i2] = fv * gg;
      sv[i2] = fmaf(gv4[i2], skwv[(oc0+i2)*12 + nt], sv[i2]);
    }
    *reinterpret_cast<uint2*>(&gh[(nt*16 + r16)*40 + oc0]) =
        make_uint2(pkh(gv4[0], gv4[1]), pkh(gv4[2], gv4[3]));
  }
#pragma unroll
  for (int i2 = 0; i2 < 4; ++i2)
    skred[((oc0+i2)*16 + r16)*2 + nh] = sv[i2];
  __syncthreads();

  // ---- phase 3: skip finalize + residual GEMM + epilogue + stats ----
  for (int e = tid; e < 512; e += 256){
    int b = e >> 5, oc = e & 31;
    float sk = skred[(oc*16+b)*2] + skred[(oc*16+b)*2+1] + skbv[oc];
    size_t so = ((size_t)b*NN + n)*32 + oc;
    if (layer == 0){
      float s0 = s0bv[oc];
#pragma unroll
      for (int r = 0; r < 24; ++r) s0 = fmaf(xin[b*24+r], s0wv[oc*24+r], s0);
      skipbuf[so] = sk + s0;
    } else {
      skipbuf[so] += sk;
    }
  }
  {
    f16x8 ar = *reinterpret_cast<const f16x8*>(&rwh[(h*16 + r16)*40 + c0]);
    float s1 = 0.f, s2 = 0.f;
#pragma unroll
    for (int q = 0; q < 6; ++q){
      int nt = nh*6 + q;
      f16x8 bg = *reinterpret_cast<const f16x8*>(&gh[(nt*16 + r16)*40 + c0]);
      f32x4 z = {0.f,0.f,0.f,0.f};
      f32x4 acc = __builtin_amdgcn_mfma_f32_16x16x32_f16(ar, bg, z, 0, 0, 0);
      uint2 xu = *reinterpret_cast<const uint2*>(&xh[(nt*16 + r16)*40 + oc0]);
      U32H2 ua, ub; ua.u = xu.x; ub.u = xu.y;
      float o0 = acc[0] + rb4[0] + (float)ua.h[0];
      float o1 = acc[1] + rb4[1] + (float)ua.h[1];
      float o2 = acc[2] + rb4[2] + (float)ub.h[0];
      float o3 = acc[3] + rb4[3] + (float)ub.h[1];
      *reinterpret_cast<float4*>(
          xbuf + (((size_t)r16*NN + n)*12 + nt)*32 + oc0) =
          make_float4(o0, o1, o2, o3);
      s1 += o0 + o1 + o2 + o3;
      s2 = fmaf(o0,o0, fmaf(o1,o1, fmaf(o2,o2, fmaf(o3,o3, s2))));
    }
    s1 += __shfl_xor(s1, 16); s2 += __shfl_xor(s2, 16);
    s1 += __shfl_xor(s1, 32); s2 += __shfl_xor(s2, 32);
    if (hi4 == 0){
      wred[(w*16 + r16)*2]     = s1;
      wred[(w*16 + r16)*2 + 1] = s2;
    }
  }
  __syncthreads();
  if (tid < 16){
    float a1 = 0.f, a2 = 0.f;
    for (int w2 = 0; w2 < 4; ++w2){
      a1 += wred[(w2*16 + tid)*2];
      a2 += wred[(w2*16 + tid)*2 + 1];
    }
    atomicAdd(&stats[layer*32 + tid], a1);
    atomicAdd(&stats[layer*32 + 16 + tid], a2);
  }
}

__global__ __launch_bounds__(256) void k_final(
    const float* __restrict__ xbuf, const float* __restrict__ skipbuf,
    const float* __restrict__ stats,
    const float* __restrict__ lnw_all, const float* __restrict__ lnb_all,
    const float* __restrict__ skEw, const float* __restrict__ skEb,
    const float* __restrict__ e1w, const float* __restrict__ e1b,
    const float* __restrict__ e2w, const float* __restrict__ e2b,
    float* __restrict__ out)
{
  __shared__ float lnw[384], lnb[384], skE[384];
  __shared__ float e1[32*33];
  __shared__ float e1bv[32], e2v[32], skEbv[32];
  __shared__ float muv[16], rsv[16];
  __shared__ float skf[8][33];
  const int tid = threadIdx.x, n = blockIdx.x;
  for (int i = tid; i < 384; i += 256){
    int c = i/12, t = i%12;
    size_t o = (((size_t)2*32 + c)*NN + n)*12 + t;
    lnw[i] = lnw_all[o]; lnb[i] = lnb_all[o];
    skE[i] = skEw[i];
  }
  for (int i = tid; i < 1024; i += 256) e1[(i>>5)*33 + (i&31)] = e1w[i];
  if (tid < 32){ e1bv[tid] = e1b[tid]; e2v[tid] = e2w[tid]; skEbv[tid] = skEb[tid]; }
  if (tid < 16){
    float S1 = stats[64+tid], S2 = stats[80+tid];
    const float M = 768000.0f;
    float mu = S1/M; muv[tid] = mu;
    rsv[tid] = rsqrtf(S2/M - mu*mu + 1e-5f);
  }
  __syncthreads();
  const float e2b0 = e2b[0];
  for (int bo = 0; bo < 2; ++bo){
    const int g = tid >> 5, c = tid & 31, b = bo*8 + g;
    float xr[12];
#pragma unroll
    for (int t = 0; t < 12; ++t)
      xr[t] = xbuf[(((size_t)b*NN + n)*12 + t)*32 + c];
    const float mu = muv[b], rs = rsv[b];
    float se = 0.0f;
#pragma unroll
    for (int t = 0; t < 12; ++t){
      float xv = fmaf((xr[t]-mu)*rs, lnw[c*12+t], lnb[c*12+t]);
      se = fmaf(xv, skE[c*12+t], se);
    }
    float sk = se + skEbv[c] + skipbuf[((size_t)b*NN+n)*32 + c];
    skf[g][c] = fmaxf(sk, 0.0f);
    __syncthreads();
    float acc = e1bv[c];
#pragma unroll
    for (int cc = 0; cc < 32; ++cc) acc = fmaf(skf[g][cc], e1[c*33+cc], acc);
    float y1 = fmaxf(acc, 0.0f);
    float part = y1 * e2v[c];
#pragma unroll
    for (int off = 16; off > 0; off >>= 1) part += __shfl_down(part, off, 32);
    if (c == 0) out[(size_t)b*NN + n] = part + e2b0;
    __syncthreads();
  }
}

extern "C" void kernel_launch(void* const* d_in, const int* in_sizes, int n_in,
                              void* d_out, int out_size, void* d_ws, size_t ws_size,
                              hipStream_t stream)
{
  (void)in_sizes; (void)n_in; (void)out_size; (void)ws_size;
  const float* input   = (const float*)d_in[0];
  const float* adj     = (const float*)d_in[1];
  const float* charac  = (const float*)d_in[2];
  const float* Wcw     = (const float*)d_in[3];
  const float* bcw     = (const float*)d_in[4];
  const float* Wcb     = (const float*)d_in[5];
  const float* bcb     = (const float*)d_in[6];
  const float* Wgw     = (const float*)d_in[7];
  const float* bgw     = (const float*)d_in[8];
  const float* Wgb     = (const float*)d_in[9];
  const float* bgb     = (const float*)d_in[10];
  const float* Wrw     = (const float*)d_in[11];
  const float* brw     = (const float*)d_in[12];
  const float* Wrb     = (const float*)d_in[13];
  const float* brb     = (const float*)d_in[14];
  const float* start_w = (const float*)d_in[15];
  const float* start_b = (const float*)d_in[16];
  const float* sk0w    = (const float*)d_in[17];
  const float* sk0b    = (const float*)d_in[18];
  const float* skw     = (const float*)d_in[19];
  const float* skb     = (const float*)d_in[20];
  const float* skEw    = (const float*)d_in[21];
  const float* skEb    = (const float*)d_in[22];
  const float* lnw     = (const float*)d_in[23];
  const float* lnb     = (const float*)d_in[24];
  const float* e1w     = (const float*)d_in[25];
  const float* e1b     = (const float*)d_in[26];
  const float* e2w     = (const float*)d_in[27];
  const float* e2b     = (const float*)d_in[28];

  float* ws     = (float*)d_ws;
  float* xbuf   = ws + XOFF;
  float* skipb  = ws + SKOFF;
  float* chbuf  = ws + CHOFF;
  float* cmbuf  = ws + CMOFF;
  float* stats  = ws + STOFF;
  float* outp   = (float*)d_out;

  k_init<<<1, 128, 0, stream>>>(stats);
  k_charm<<<32, 256, 0, stream>>>(input, charac, cmbuf);
  k_ch<<<NN, 256, 0, stream>>>(adj, cmbuf, chbuf);
  for (int layer = 0; layer < 3; ++layer){
    k_layer<<<NN, 256, 0, stream>>>(layer, xbuf, skipb, chbuf, stats, input,
        Wcw, bcw, Wcb, bcb, Wgw, bgw, Wgb, bgb, Wrw, brw, Wrb, brb,
        start_w, start_b, sk0w, sk0b, skw, skb, lnw, lnb);
  }
  k_final<<<NN, 256, 0, stream>>>(xbuf, skipb, stats, lnw, lnb,
      skEw, skEb, e1w, e1b, e2w, e2b, outp);
}

// Round 6
// 285.742 us; speedup vs baseline: 1.8010x; 1.0946x over previous
//
#include <hip/hip_runtime.h>

#define NN 2000
#define TT 12

// workspace layout (in floats)
#define XOFF   0          // x buffer: (B,N,T,C) = 16*2000*12*32
#define SKOFF  12288000   // skip: (B,N,C)
#define CHOFF  13312000   // ch: N*4
#define CMOFF  13320000   // char_m: N*4
#define STOFF  13328000   // stats: 3 layers * 32 (S1[16], S2[16])

typedef __fp16 f16x8 __attribute__((ext_vector_type(8)));
typedef float  f32x4 __attribute__((ext_vector_type(4)));

union U32H2 { unsigned int u; __fp16 h[2]; };
__device__ __forceinline__ unsigned int pkh(float a, float b){
  U32H2 v; v.h[0] = (__fp16)a; v.h[1] = (__fp16)b; return v.u;
}
__device__ __forceinline__ float fsig(float x){ return 1.0f/(1.0f + __expf(-x)); }
__device__ __forceinline__ float ftanh(float x){ return 1.0f - 2.0f/(1.0f + __expf(2.0f*x)); }

__global__ void k_init(float* stats){
  int t = threadIdx.x;
  if (t < 96) stats[t] = 0.0f;
}

__global__ void k_charm(const float* __restrict__ input,
                        const float* __restrict__ charac,
                        float* __restrict__ cm)
{
  int idx = blockIdx.x*256 + threadIdx.x;
  if (idx >= NN*4) return;
  int n = idx >> 2, r = idx & 3;
  int mv = (int)input[TT];
  int m = ((mv % 12) + 12) % 12;
  int m0 = (m + 11) % 12, m2 = (m + 1) % 12;
  const float* base = charac + n*48;
  cm[idx] = (base[m0*4+r] + base[m*4+r] + base[m2*4+r]) * (1.0f/3.0f);
}

__global__ __launch_bounds__(256) void k_ch(const float* __restrict__ adj,
                                            const float* __restrict__ cm,
                                            float* __restrict__ ch)
{
  __shared__ float red[256][4];
  int n = blockIdx.x, t = threadIdx.x;
  float s0=0.f, s1=0.f, s2=0.f, s3=0.f;
  const float* arow = adj + (size_t)n*NN;
  for (int c = t; c < NN; c += 256){
    float a = arow[c];
    float4 v = *reinterpret_cast<const float4*>(cm + c*4);
    s0 = fmaf(a, v.x, s0); s1 = fmaf(a, v.y, s1);
    s2 = fmaf(a, v.z, s2); s3 = fmaf(a, v.w, s3);
  }
  red[t][0]=s0; red[t][1]=s1; red[t][2]=s2; red[t][3]=s3;
  __syncthreads();
  for (int off = 128; off > 0; off >>= 1){
    if (t < off){
      red[t][0]+=red[t+off][0]; red[t][1]+=red[t+off][1];
      red[t][2]+=red[t+off][2]; red[t][3]+=red[t+off][3];
    }
    __syncthreads();
  }
  if (t < 4) ch[n*4+t] = red[0][t];
}

// ---------------------------------------------------------------------------
// k_layer, R6: split-K A tiles + gh overlay + 3 blocks/CU.
// A tiles in AhG: A0f[16][104] @0 (oc 0..15, K=96: slices k=2,3),
// A0g @16*104, A1f[16][232] @3328 (oc 16..31, K=224: slices k=6,7),
// A1g @3328+16*232. After phase-2 fragment loads + barrier, AhG is reused
// as gh[12][16][40] (gated output f16).
// ---------------------------------------------------------------------------
__global__ __launch_bounds__(256,3) void k_layer(
    int layer,
    float* __restrict__ xbuf, float* __restrict__ skipbuf,
    const float* __restrict__ ch, float* stats,
    const float* __restrict__ input,
    const float* __restrict__ Wcw, const float* __restrict__ bcw,
    const float* __restrict__ Wcb, const float* __restrict__ bcb,
    const float* __restrict__ Wgw, const float* __restrict__ bgw,
    const float* __restrict__ Wgb, const float* __restrict__ bgb,
    const float* __restrict__ Wrw, const float* __restrict__ brw,
    const float* __restrict__ Wrb, const float* __restrict__ brb,
    const float* __restrict__ start_w, const float* __restrict__ start_b,
    const float* __restrict__ sk0w, const float* __restrict__ sk0b,
    const float* __restrict__ skw_all, const float* __restrict__ skb_all,
    const float* __restrict__ lnw_all, const float* __restrict__ lnb_all)
{
  __shared__ __fp16 AhG[10752];      // 21504 B  (A tiles, later gh overlay)
  __shared__ __fp16 xh[7680];        // 15360 B  [t][b][c] stride 40
  __shared__ __fp16 rwh[1280];       //  2560 B  [oc][c] stride 40
  __shared__ float skred[1024];      //  4096 B
  __shared__ float wred[128];        //   512 B
  __shared__ float ubuf[1280];       //  5120 B
  __shared__ float skwv[384];        //  1536 B
  __shared__ float skbv[32], fbias[32], gbias[32], rbv[32];
  __shared__ float muv[16], rsv[16];

  const int tid = threadIdx.x;
  const int n = blockIdx.x;

  float* swv  = ubuf;        // 64   (layer 0)
  float* sbv  = ubuf + 64;   // 32
  float* s0wv = ubuf + 96;   // 768
  float* s0bv = ubuf + 864;  // 32
  float* xin  = ubuf + 896;  // 384 = 16 b x 24
  float* lnwv = ubuf;        // 384  (layer > 0), [c*12+t]
  float* lnbv = ubuf + 384;  // 384

  // ---- ch direct (L1-broadcast), no LDS round-trip ----
  const float c0v = ch[n*4+0], c1v = ch[n*4+1], c2v = ch[n*4+2], c3v = ch[n*4+3];

  // ---- phase 0 constants (no barrier needed before weight-gen) ----
  for (int i = tid; i < 32; i += 256) skbv[i] = skb_all[layer*32+i];
  for (int i = tid; i < 384; i += 256) skwv[i] = skw_all[layer*384+i];
  if (layer == 0){
    for (int i = tid; i < 64; i += 256) swv[i] = start_w[i];
    for (int i = tid; i < 32; i += 256){ sbv[i] = start_b[i]; s0bv[i] = sk0b[i]; }
    for (int i = tid; i < 768; i += 256) s0wv[i] = sk0w[i];
    for (int i = tid; i < 384; i += 256){
      int bb = i/24, r = i%24, d = r/12, t = r%12;
      xin[i] = input[(((size_t)bb*2 + d)*NN + n)*13 + t];
    }
  } else {
    for (int i = tid; i < 384; i += 256){
      int c = i/12, t = i%12;
      size_t o = (((size_t)(layer-1)*32 + c)*NN + n)*12 + t;
      lnwv[i] = lnw_all[o]; lnbv[i] = lnb_all[o];
    }
    if (tid < 16){
      float S1 = stats[(layer-1)*32 + tid];
      float S2 = stats[(layer-1)*32 + 16 + tid];
      const float M = 768000.0f;
      float mu = S1 / M;
      muv[tid] = mu;
      rsv[tid] = rsqrtf(S2/M - mu*mu + 1e-5f);
    }
  }

  // ---- phase 1: weight gen into split-K tiles (coalesced global loads) ----
  for (int i = tid; i < 4608; i += 256){
    int o   = i / 576;
    int rem = i - o*576;
    int c   = rem / 18;
    int u   = rem - c*18;
    int s   = (u >= 2) + (u >= 5) + (u >= 11);
    int lo  = (s == 0) ? 0 : ((s == 1) ? 2 : ((s == 2) ? 5 : 11));
    int jj  = u - lo;
    int col = layer*4608 + i;
    float wf = fmaf(c0v, Wcw[col], fmaf(c1v, Wcw[13824+col],
               fmaf(c2v, Wcw[27648+col], fmaf(c3v, Wcw[41472+col], bcw[col]))));
    float wg = fmaf(c0v, Wgw[col], fmaf(c1v, Wgw[13824+col],
               fmaf(c2v, Wgw[27648+col], fmaf(c3v, Wgw[41472+col], bgw[col]))));
    int base = (s >= 2) ? 3328 : 0;
    int strd = (s >= 2) ? 232 : 104;
    int r    = ((s & 1) << 3) + o;
    int k    = jj*32 + c;
    AhG[base + r*strd + k]              = (__fp16)wf;
    AhG[base + (16 + r)*strd + k]       = (__fp16)wg;
  }
  // zero the 1024 padding slots (s=0 jj=2; s=2 jj=6), disjoint from writes above
  for (int i = tid; i < 1024; i += 256){
    int grp = i >> 8, rem = i & 255, r = rem >> 5, c = rem & 31;
    int base = (grp < 2) ? 0 : 3328;
    int strd = (grp < 2) ? 104 : 232;
    int off  = (grp < 2) ? 64 : 192;
    int gofs = (grp & 1) ? 16*strd : 0;
    AhG[base + gofs + r*strd + off + c] = (__fp16)0.f;
  }
  for (int i = tid; i < 1024; i += 256){
    int col = layer*1024 + i;
    float v = fmaf(c0v, Wrw[col], fmaf(c1v, Wrw[3072+col],
              fmaf(c2v, Wrw[6144+col], fmaf(c3v, Wrw[9216+col], brw[col]))));
    rwh[(i>>5)*40 + (i&31)] = (__fp16)v;
  }
  if (tid < 32){
    int oc = tid;
    int s = oc >> 3;
    int v = ((n&3)<<3) + (oc&7);               // bias reshuffle: column
    int col = layer*32 + v;
    float cb0 = ch[(s*500 + (n>>2))*4 + 0];
    float cb1 = ch[(s*500 + (n>>2))*4 + 1];
    float cb2 = ch[(s*500 + (n>>2))*4 + 2];
    float cb3 = ch[(s*500 + (n>>2))*4 + 3];
    fbias[oc] = fmaf(cb0, Wcb[col], fmaf(cb1, Wcb[96+col],
                fmaf(cb2, Wcb[192+col], fmaf(cb3, Wcb[288+col], bcb[col]))));
    gbias[oc] = fmaf(cb0, Wgb[col], fmaf(cb1, Wgb[96+col],
                fmaf(cb2, Wgb[192+col], fmaf(cb3, Wgb[288+col], bgb[col]))));
    int colr = layer*32 + oc;
    rbv[oc] = fmaf(c0v, Wrb[colr], fmaf(c1v, Wrb[96+colr],
              fmaf(c2v, Wrb[192+colr], fmaf(c3v, Wrb[288+colr], brb[colr]))));
  }
  __syncthreads();

  // ---- staging: xh[t][b][c] f16 ----
  if (tid < 192){
    int b = tid / 12, t = tid - (tid/12)*12;
    float xv[32];
    if (layer == 0){
      float xa = xin[b*24 + t], xb2 = xin[b*24 + 12 + t];
#pragma unroll
      for (int c = 0; c < 32; ++c)
        xv[c] = fmaf(swv[c*2], xa, fmaf(swv[c*2+1], xb2, sbv[c]));
    } else {
      const float4* src = reinterpret_cast<const float4*>(
          xbuf + (((size_t)b*NN + n)*12 + t)*32);
      float mu = muv[b], rs = rsv[b];
#pragma unroll
      for (int c4 = 0; c4 < 8; ++c4){
        float4 v = src[c4];
        int c = c4*4;
        xv[c]   = fmaf((v.x-mu)*rs, lnwv[(c)*12+t],   lnbv[(c)*12+t]);
        xv[c+1] = fmaf((v.y-mu)*rs, lnwv[(c+1)*12+t], lnbv[(c+1)*12+t]);
        xv[c+2] = fmaf((v.z-mu)*rs, lnwv[(c+2)*12+t], lnbv[(c+2)*12+t]);
        xv[c+3] = fmaf((v.w-mu)*rs, lnwv[(c+3)*12+t], lnbv[(c+3)*12+t]);
      }
    }
    unsigned int pk[16];
#pragma unroll
    for (int j = 0; j < 16; ++j) pk[j] = pkh(xv[2*j], xv[2*j+1]);
    uint4* dst = reinterpret_cast<uint4*>(&xh[(t*16 + b)*40]);
    dst[0] = make_uint4(pk[0], pk[1], pk[2], pk[3]);
    dst[1] = make_uint4(pk[4], pk[5], pk[6], pk[7]);
    dst[2] = make_uint4(pk[8], pk[9], pk[10], pk[11]);
    dst[3] = make_uint4(pk[12],pk[13],pk[14],pk[15]);
  }
  __syncthreads();

  // ---- phase 2: load A frags, barrier (frees AhG), MFMA conv ----
  const int lane = tid & 63, w = tid >> 6;
  const int h = w & 1, nh = w >> 1;
  const int r16 = lane & 15, hi4 = lane >> 4;
  const int c0 = hi4*8;
  const int oc0 = h*16 + hi4*4;

  const __fp16* Ab = AhG + (h ? 3328 : 0);
  const int As  = h ? 232 : 104;
  const int njj = h ? 7 : 3;
  f16x8 aF[7], aG[7];
#pragma unroll 7
  for (int jj = 0; jj < 7; ++jj) if (jj < njj){
    aF[jj] = *reinterpret_cast<const f16x8*>(&Ab[r16*As + jj*32 + c0]);
    aG[jj] = *reinterpret_cast<const f16x8*>(&Ab[(16 + r16)*As + jj*32 + c0]);
  }
  f16x8 ar = *reinterpret_cast<const f16x8*>(&rwh[(h*16 + r16)*40 + c0]);
  float fb4[4], gb4[4], rb4[4];
#pragma unroll
  for (int i2 = 0; i2 < 4; ++i2){
    fb4[i2] = fbias[oc0+i2]; gb4[i2] = gbias[oc0+i2]; rb4[i2] = rbv[oc0+i2];
  }
  __syncthreads();                    // all A frags in regs -> AhG reusable
  __fp16* gh = AhG;                   // gh[t][b][c], stride 40

  float sv[4] = {0.f, 0.f, 0.f, 0.f};
#pragma unroll
  for (int q = 0; q < 6; ++q){
    int nt = nh*6 + q;
    f32x4 accf = {0.f,0.f,0.f,0.f}, accg = {0.f,0.f,0.f,0.f};
#pragma unroll 7
    for (int jj = 0; jj < 7; ++jj) if (jj < njj){
      int tp = nt + jj; if (tp >= 12) tp -= 12;
      f16x8 bf = *reinterpret_cast<const f16x8*>(&xh[(tp*16 + r16)*40 + c0]);
      accf = __builtin_amdgcn_mfma_f32_16x16x32_f16(aF[jj], bf, accf, 0, 0, 0);
      accg = __builtin_amdgcn_mfma_f32_16x16x32_f16(aG[jj], bf, accg, 0, 0, 0);
    }
    float gv4[4];
#pragma unroll
    for (int i2 = 0; i2 < 4; ++i2){
      float fv = ftanh(accf[i2] + fb4[i2]);
      float gg = fsig(accg[i2] + gb4[i2]);
      gv4[i2] = fv * gg;
      sv[i2] = fmaf(gv4[i2], skwv[(oc0+i2)*12 + nt], sv[i2]);
    }
    *reinterpret_cast<uint2*>(&gh[(nt*16 + r16)*40 + oc0]) =
        make_uint2(pkh(gv4[0], gv4[1]), pkh(gv4[2], gv4[3]));
  }
#pragma unroll
  for (int i2 = 0; i2 < 4; ++i2)
    skred[((oc0+i2)*16 + r16)*2 + nh] = sv[i2];
  __syncthreads();

  // ---- phase 3: skip finalize + residual GEMM + epilogue + stats ----
  for (int e = tid; e < 512; e += 256){
    int b = e >> 5, oc = e & 31;
    float sk = skred[(oc*16+b)*2] + skred[(oc*16+b)*2+1] + skbv[oc];
    size_t so = ((size_t)b*NN + n)*32 + oc;
    if (layer == 0){
      float s0 = s0bv[oc];
#pragma unroll
      for (int r = 0; r < 24; ++r) s0 = fmaf(xin[b*24+r], s0wv[oc*24+r], s0);
      skipbuf[so] = sk + s0;
    } else {
      skipbuf[so] += sk;
    }
  }
  {
    float s1 = 0.f, s2 = 0.f;
#pragma unroll
    for (int q = 0; q < 6; ++q){
      int nt = nh*6 + q;
      f16x8 bg = *reinterpret_cast<const f16x8*>(&gh[(nt*16 + r16)*40 + c0]);
      f32x4 z = {0.f,0.f,0.f,0.f};
      f32x4 acc = __builtin_amdgcn_mfma_f32_16x16x32_f16(ar, bg, z, 0, 0, 0);
      uint2 xu = *reinterpret_cast<const uint2*>(&xh[(nt*16 + r16)*40 + oc0]);
      U32H2 ua, ub; ua.u = xu.x; ub.u = xu.y;
      float o0 = acc[0] + rb4[0] + (float)ua.h[0];
      float o1 = acc[1] + rb4[1] + (float)ua.h[1];
      float o2 = acc[2] + rb4[2] + (float)ub.h[0];
      float o3 = acc[3] + rb4[3] + (float)ub.h[1];
      *reinterpret_cast<float4*>(
          xbuf + (((size_t)r16*NN + n)*12 + nt)*32 + oc0) =
          make_float4(o0, o1, o2, o3);
      s1 += o0 + o1 + o2 + o3;
      s2 = fmaf(o0,o0, fmaf(o1,o1, fmaf(o2,o2, fmaf(o3,o3, s2))));
    }
    s1 += __shfl_xor(s1, 16); s2 += __shfl_xor(s2, 16);
    s1 += __shfl_xor(s1, 32); s2 += __shfl_xor(s2, 32);
    if (hi4 == 0){
      wred[(w*16 + r16)*2]     = s1;
      wred[(w*16 + r16)*2 + 1] = s2;
    }
  }
  __syncthreads();
  if (tid < 16){
    float a1 = 0.f, a2 = 0.f;
    for (int w2 = 0; w2 < 4; ++w2){
      a1 += wred[(w2*16 + tid)*2];
      a2 += wred[(w2*16 + tid)*2 + 1];
    }
    atomicAdd(&stats[layer*32 + tid], a1);
    atomicAdd(&stats[layer*32 + 16 + tid], a2);
  }
}

__global__ __launch_bounds__(256) void k_final(
    const float* __restrict__ xbuf, const float* __restrict__ skipbuf,
    const float* __restrict__ stats,
    const float* __restrict__ lnw_all, const float* __restrict__ lnb_all,
    const float* __restrict__ skEw, const float* __restrict__ skEb,
    const float* __restrict__ e1w, const float* __restrict__ e1b,
    const float* __restrict__ e2w, const float* __restrict__ e2b,
    float* __restrict__ out)
{
  __shared__ float lnw[384], lnb[384], skE[384];
  __shared__ float e1[32*33];
  __shared__ float e1bv[32], e2v[32], skEbv[32];
  __shared__ float muv[16], rsv[16];
  __shared__ float skf[8][33];
  const int tid = threadIdx.x, n = blockIdx.x;
  for (int i = tid; i < 384; i += 256){
    int c = i/12, t = i%12;
    size_t o = (((size_t)2*32 + c)*NN + n)*12 + t;
    lnw[i] = lnw_all[o]; lnb[i] = lnb_all[o];
    skE[i] = skEw[i];
  }
  for (int i = tid; i < 1024; i += 256) e1[(i>>5)*33 + (i&31)] = e1w[i];
  if (tid < 32){ e1bv[tid] = e1b[tid]; e2v[tid] = e2w[tid]; skEbv[tid] = skEb[tid]; }
  if (tid < 16){
    float S1 = stats[64+tid], S2 = stats[80+tid];
    const float M = 768000.0f;
    float mu = S1/M; muv[tid] = mu;
    rsv[tid] = rsqrtf(S2/M - mu*mu + 1e-5f);
  }
  __syncthreads();
  const float e2b0 = e2b[0];
  for (int bo = 0; bo < 2; ++bo){
    const int g = tid >> 5, c = tid & 31, b = bo*8 + g;
    float xr[12];
#pragma unroll
    for (int t = 0; t < 12; ++t)
      xr[t] = xbuf[(((size_t)b*NN + n)*12 + t)*32 + c];
    const float mu = muv[b], rs = rsv[b];
    float se = 0.0f;
#pragma unroll
    for (int t = 0; t < 12; ++t){
      float xv = fmaf((xr[t]-mu)*rs, lnw[c*12+t], lnb[c*12+t]);
      se = fmaf(xv, skE[c*12+t], se);
    }
    float sk = se + skEbv[c] + skipbuf[((size_t)b*NN+n)*32 + c];
    skf[g][c] = fmaxf(sk, 0.0f);
    __syncthreads();
    float acc = e1bv[c];
#pragma unroll
    for (int cc = 0; cc < 32; ++cc) acc = fmaf(skf[g][cc], e1[c*33+cc], acc);
    float y1 = fmaxf(acc, 0.0f);
    float part = y1 * e2v[c];
#pragma unroll
    for (int off = 16; off > 0; off >>= 1) part += __shfl_down(part, off, 32);
    if (c == 0) out[(size_t)b*NN + n] = part + e2b0;
    __syncthreads();
  }
}

extern "C" void kernel_launch(void* const* d_in, const int* in_sizes, int n_in,
                              void* d_out, int out_size, void* d_ws, size_t ws_size,
                              hipStream_t stream)
{
  (void)in_sizes; (void)n_in; (void)out_size; (void)ws_size;
  const float* input   = (const float*)d_in[0];
  const float* adj     = (const float*)d_in[1];
  const float* charac  = (const float*)d_in[2];
  const float* Wcw     = (const float*)d_in[3];
  const float* bcw     = (const float*)d_in[4];
  const float* Wcb     = (const float*)d_in[5];
  const float* bcb     = (const float*)d_in[6];
  const float* Wgw     = (const float*)d_in[7];
  const float* bgw     = (const float*)d_in[8];
  const float* Wgb     = (const float*)d_in[9];
  const float* bgb     = (const float*)d_in[10];
  const float* Wrw     = (const float*)d_in[11];
  const float* brw     = (const float*)d_in[12];
  const float* Wrb     = (const float*)d_in[13];
  const float* brb     = (const float*)d_in[14];
  const float* start_w = (const float*)d_in[15];
  const float* start_b = (const float*)d_in[16];
  const float* sk0w    = (const float*)d_in[17];
  const float* sk0b    = (const float*)d_in[18];
  const float* skw     = (const float*)d_in[19];
  const float* skb     = (const float*)d_in[20];
  const float* skEw    = (const float*)d_in[21];
  const float* skEb    = (const float*)d_in[22];
  const float* lnw     = (const float*)d_in[23];
  const float* lnb     = (const float*)d_in[24];
  const float* e1w     = (const float*)d_in[25];
  const float* e1b     = (const float*)d_in[26];
  const float* e2w     = (const float*)d_in[27];
  const float* e2b     = (const float*)d_in[28];

  float* ws     = (float*)d_ws;
  float* xbuf   = ws + XOFF;
  float* skipb  = ws + SKOFF;
  float* chbuf  = ws + CHOFF;
  float* cmbuf  = ws + CMOFF;
  float* stats  = ws + STOFF;
  float* outp   = (float*)d_out;

  k_init<<<1, 128, 0, stream>>>(stats);
  k_charm<<<32, 256, 0, stream>>>(input, charac, cmbuf);
  k_ch<<<NN, 256, 0, stream>>>(adj, cmbuf, chbuf);
  for (int layer = 0; layer < 3; ++layer){
    k_layer<<<NN, 256, 0, stream>>>(layer, xbuf, skipb, chbuf, stats, input,
        Wcw, bcw, Wcb, bcb, Wgw, bgw, Wgb, bgb, Wrw, brw, Wrb, brb,
        start_w, start_b, sk0w, sk0b, skw, skb, lnw, lnb);
  }
  k_final<<<NN, 256, 0, stream>>>(xbuf, skipb, stats, lnw, lnb,
      skEw, skEb, e1w, e1b, e2w, e2b, outp);
}